// Round 8
// baseline (4462.970 us; speedup 1.0000x reference)
//
#include <hip/hip_runtime.h>
#include <hip/hip_bf16.h>
#include <stdint.h>

#define BATCH 64
#define SEQ   512
#define HID   1024
#define VOC   4096
#define LROWS (SEQ*BATCH)   // 32768 output rows
#define HN    (BATCH*HID)   // 65536 elems per H state
#define NWG   64
#define NGRP  8             // init barrier tree: 8 groups x 8 wgs
#define GSZ   8
#define PFN   ((SEQ + 1) * 4 * 64)   // per-(step,wave,wg) flags

typedef __attribute__((ext_vector_type(4))) float f32x4;
typedef __attribute__((ext_vector_type(8))) short short8;

__device__ __forceinline__ unsigned short f2bf(float f) {
    unsigned int u = __builtin_bit_cast(unsigned int, f);
    u += 0x7fffu + ((u >> 16) & 1u);   // round-to-nearest-even
    return (unsigned short)(u >> 16);
}

__device__ __forceinline__ float tanh_fast(float x) {
    // |z| stays O(1) here; e^{2x} cannot overflow. rel err ~1e-6.
    float e = __expf(2.f * x);
    return (e - 1.f) * __frcp_rn(e + 1.f);
}

// Write-through-to-LLC bf16 store: visible device-wide once vmcnt retires.
__device__ __forceinline__ void store_bf16_llc(unsigned short* p, unsigned short v) {
    unsigned int vv = v;
    asm volatile("global_store_short %0, %1, off sc0 sc1" :: "v"(p), "v"(vv) : "memory");
}

// async global->LDS, 16B per lane (gemm only)
#define GLL16(g, l) __builtin_amdgcn_global_load_lds( \
    (const __attribute__((address_space(1))) void*)(g), \
    (__attribute__((address_space(3))) void*)(l), 16, 0, 0)

// ---------------------------------------------------------------------------
// One-time tree barrier (init only). Same all-relaxed scheme as round 7.
// ---------------------------------------------------------------------------
__device__ __forceinline__ void gbar_tree(unsigned* bar, unsigned gen, int grp) {
    asm volatile("s_waitcnt vmcnt(0)" ::: "memory");  // drain sc-stores
    __syncthreads();
    if (threadIdx.x == 0) {
        unsigned* lcnt  = bar + grp*32;
        unsigned* gcnt  = bar + 8*32;
        unsigned* relay = bar + (16 + grp)*32;
        unsigned a = __hip_atomic_fetch_add(lcnt, 1u, __ATOMIC_RELAXED,
                                            __HIP_MEMORY_SCOPE_AGENT);
        if (a + 1u == gen * GSZ) {
            unsigned go = __hip_atomic_fetch_add(gcnt, 1u, __ATOMIC_RELAXED,
                                                 __HIP_MEMORY_SCOPE_AGENT);
            if (go + 1u < gen * NGRP) {
                unsigned c;
                do {
                    __builtin_amdgcn_s_sleep(1);
                    c = __hip_atomic_load(gcnt, __ATOMIC_RELAXED,
                                          __HIP_MEMORY_SCOPE_AGENT);
                } while (c < gen * NGRP);
            }
            __hip_atomic_store(relay, gen, __ATOMIC_RELAXED,
                               __HIP_MEMORY_SCOPE_AGENT);
        } else {
            unsigned r;
            do {
                __builtin_amdgcn_s_sleep(1);
                r = __hip_atomic_load(relay, __ATOMIC_RELAXED,
                                      __HIP_MEMORY_SCOPE_AGENT);
            } while (r < gen);
        }
    }
    __syncthreads();
    asm volatile("" ::: "memory");
}

// ---------------------------------------------------------------------------
// Generic: in[R][C] f32  ->  out[C][R] bf16   (transpose + convert)
// ---------------------------------------------------------------------------
__global__ __launch_bounds__(256) void k_transpose_f32_bf16(
    const float* __restrict__ in, unsigned short* __restrict__ out, int R, int C)
{
    __shared__ float tile[64][65];
    const int tid = threadIdx.x;
    const int c0 = blockIdx.x * 64;
    const int r0 = blockIdx.y * 64;
    #pragma unroll
    for (int i = 0; i < 16; ++i) {
        int idx = tid + i*256;
        int r = idx >> 6, c = idx & 63;
        tile[r][c] = in[(size_t)(r0 + r)*C + c0 + c];
    }
    __syncthreads();
    #pragma unroll
    for (int i = 0; i < 16; ++i) {
        int idx = tid + i*256;
        int r = idx >> 6, c = idx & 63;
        out[(size_t)(c0 + r)*R + r0 + c] = f2bf(tile[c][r]);
    }
}

// ---------------------------------------------------------------------------
// Persistent recurrence, per-wave DATAFLOW sync (no per-step barrier).
// Wave w of wg g produces H_{t+1}[16w..16w+16)[16g..16g+16), then:
//   drain vmcnt -> set pf[t+1][w][g] (agent-scope store).
// Consumer wave (g',w') at step t polls pf[t][w'][0..63] (lane p = wg p),
// ballot-spins until all 64 set, then loads its A rows. The wait graph is a
// DAG (step t depends only on step t-1 flags) => deadlock-free given
// co-residency (cooperative launch). No __syncthreads in the main loop:
// the 4 waves of a wg run fully decoupled.
// pf is zeroed in-graph EVERY call so timed replays cannot observe stale
// flags. Data visibility: sc0sc1 write-through + vmcnt(0) drain before the
// flag store (same mechanism proven in rounds 4-7).
// ---------------------------------------------------------------------------
__global__ __launch_bounds__(256, 1) void k_rnn_persist(
    const unsigned short* __restrict__ WhhT, // [1024 c][1024 k] bf16
    const float* __restrict__ bh,            // [1024]
    const float* __restrict__ Wxh,           // [4096][1024] f32
    const int*   __restrict__ X,             // [64][512]
    const float* __restrict__ H0,            // [64][1024] f32
    unsigned short* __restrict__ Hst,        // [513][64][1024] bf16
    float* __restrict__ Hfin,                // [64][1024] f32 (out tail)
    unsigned* __restrict__ bar,              // init-barrier lines (zeroed)
    unsigned* __restrict__ pf)               // [513][4][64] flags (zeroed)
{
    __shared__ unsigned short Wl[16*1024];   // [c][k], XOR-swizzled
    const int tid  = threadIdx.x;
    const int lane = tid & 63;
    const int wave = tid >> 6;               // row-tile 16*wave
    const int g    = blockIdx.x;             // col slice
    const int grp  = g >> 3;

    // ---- stage W slice into LDS (once), swizzled: byte ^= (c&7)<<4 ----
    #pragma unroll
    for (int it = 0; it < 8; ++it) {
        int slot = it*256 + tid;             // 0..2047 (16B chunks)
        int c  = slot >> 7;                  // 0..15
        int k0 = (slot & 127) * 8;
        short8 v = *(const short8*)&WhhT[(size_t)(g*16 + c)*HID + k0];
        int byte = c*2048 + k0*2;
        byte ^= (c & 7) << 4;
        *(short8*)((char*)Wl + byte) = v;
    }
    // ---- init state slot 0 = bf16(H0): wg g writes batch row g (LLC-visible)
    for (int i = tid; i < 1024; i += 256) {
        int idx = g*1024 + i;
        store_bf16_llc(&Hst[idx], f2bf(H0[idx]));
    }

    const int col   = g*16 + (lane & 15);
    const float bhc = bh[col];
    const int rowbase = wave*16 + ((lane >> 4) * 4);

    // prefetch x-gather for t=0 (read-only data, safe before barrier)
    float xv[4];
    #pragma unroll
    for (int q = 0; q < 4; ++q) {
        int xi = X[(rowbase + q)*SEQ + 0];
        xv[q] = Wxh[(size_t)xi*HID + col];
    }

    gbar_tree(bar, 1, grp);   // one-time: slot 0 + Wl visible/ready

    for (int t = 0; t < SEQ; ++t) {
        // ---- consume: wait for my 64 producers (same wave-index, all wgs)
        if (t > 0) {
            const unsigned* pp = pf + ((size_t)t*4 + wave)*64 + lane;
            unsigned v;
            do {
                v = __hip_atomic_load(pp, __ATOMIC_RELAXED,
                                      __HIP_MEMORY_SCOPE_AGENT);
            } while (__ballot(v == 0u) != 0ull);
        }

        const unsigned short* Hin = Hst + (size_t)t * HN;
        // A fragments: rows 16w+(lane&15), k = ks*32 + (lane>>4)*8
        const unsigned short* arow =
            Hin + (size_t)(wave*16 + (lane & 15))*HID + (lane >> 4)*8;
        short8 af[32];
        #pragma unroll
        for (int ks = 0; ks < 32; ++ks)
            af[ks] = *(const short8*)(arow + ks*32);

        // prefetch next step's x-gather (H-independent; hides under MFMA)
        float xvn[4] = {0.f, 0.f, 0.f, 0.f};
        if (t + 1 < SEQ) {
            #pragma unroll
            for (int q = 0; q < 4; ++q) {
                int xi = X[(rowbase + q)*SEQ + (t + 1)];
                xvn[q] = Wxh[(size_t)xi*HID + col];
            }
        }

        // dual accumulation chains (halves dependent-MFMA latency)
        f32x4 acc0 = (f32x4){0.f, 0.f, 0.f, 0.f};
        f32x4 acc1 = (f32x4){0.f, 0.f, 0.f, 0.f};
        #pragma unroll
        for (int ks = 0; ks < 32; ks += 2) {
            int byte0 = (lane & 15)*2048 + ks*64 + (lane >> 4)*16;
            int byte1 = byte0 + 64;
            byte0 ^= (lane & 7) << 4;
            byte1 ^= (lane & 7) << 4;
            short8 b0 = *(const short8*)((char*)Wl + byte0);
            short8 b1 = *(const short8*)((char*)Wl + byte1);
            acc0 = __builtin_amdgcn_mfma_f32_16x16x32_bf16(af[ks],   b0, acc0, 0, 0, 0);
            acc1 = __builtin_amdgcn_mfma_f32_16x16x32_bf16(af[ks+1], b1, acc1, 0, 0, 0);
        }
        f32x4 acc = acc0 + acc1;

        unsigned short* Hout = Hst + (size_t)(t + 1) * HN;
        #pragma unroll
        for (int q = 0; q < 4; ++q) {
            float h = tanh_fast(acc[q] + xv[q] + bhc);
            store_bf16_llc(&Hout[(size_t)(rowbase + q)*HID + col], f2bf(h));
            if (t == SEQ - 1) Hfin[(rowbase + q)*HID + col] = h;
        }
        #pragma unroll
        for (int q = 0; q < 4; ++q) xv[q] = xvn[q];

        // ---- produce: drain my stores, then set my flag (per wave)
        if (t + 1 < SEQ) {
            asm volatile("s_waitcnt vmcnt(0)" ::: "memory");
            if (lane == 0) {
                unsigned* fp = pf + ((size_t)(t + 1)*4 + wave)*64 + g;
                __hip_atomic_store(fp, 1u, __ATOMIC_RELAXED,
                                   __HIP_MEMORY_SCOPE_AGENT);
            }
        }
        // t == SEQ-1: slot-512/Hfin stores complete at kernel end (stream order)
    }
}

// ---------------------------------------------------------------------------
// Logits GEMM: C[L][4096] = A[L][1024](bf16) * Bt[4096][1024]^T(bf16) + b_q
// 128x128 tile, BK=64, 4 waves (2x2); XCD-aware block swizzle (8192 % 8 == 0)
// ---------------------------------------------------------------------------
__global__ __launch_bounds__(256) void k_gemm_logits(
    const unsigned short* __restrict__ A,   // [LROWS][1024] bf16
    const unsigned short* __restrict__ Bt,  // [4096][1024] bf16
    const float* __restrict__ bq,           // [4096]
    float* __restrict__ C)                  // [LROWS][4096]
{
    __shared__ unsigned short lA[128*64];   // row stride 64 bf16 (128B)
    __shared__ unsigned short lB[128*64];
    const int tid  = threadIdx.x;
    const int lane = tid & 63;
    const int wave = tid >> 6;
    const int wm = wave >> 1, wn = wave & 1;

    const int NBM = LROWS/128, NBN = VOC/128;          // 256 x 32 = 8192
    int lid = blockIdx.y * NBM + blockIdx.x;
    int swz = (lid & 7) * (NBM*NBN/8) + (lid >> 3);
    const int bm = swz % NBM;
    const int bn = swz / NBM;
    const int rowA0 = bm * 128;
    const int rowB0 = bn * 128;

    f32x4 acc[4][4];
    #pragma unroll
    for (int i = 0; i < 4; ++i)
        #pragma unroll
        for (int j = 0; j < 4; ++j)
            acc[i][j] = (f32x4){0.f, 0.f, 0.f, 0.f};

    for (int kt = 0; kt < HID; kt += 64) {
        __syncthreads();
        #pragma unroll
        for (int i = 0; i < 4; ++i) {
            int slot = i*256 + tid;          // 16B slots, 8 per tile row
            int row  = slot >> 3;
            int colb = (slot & 7) * 8;       // bf16 col
            const unsigned short* ga = A  + (size_t)(rowA0 + row)*HID + kt + colb;
            const unsigned short* gb = Bt + (size_t)(rowB0 + row)*HID + kt + colb;
            unsigned short* la = lA + (i*256 + (tid >> 6)*64)*8;  // wave-uniform
            unsigned short* lb = lB + (i*256 + (tid >> 6)*64)*8;
            GLL16(ga, la);
            GLL16(gb, lb);
        }
        __syncthreads();
        #pragma unroll
        for (int ks = 0; ks < 2; ++ks) {
            short8 af[4], bf[4];
            #pragma unroll
            for (int i = 0; i < 4; ++i) {
                int row = wm*64 + i*16 + (lane & 15);
                int k   = ks*32 + (lane >> 4)*8;
                af[i] = *(const short8*)&lA[row*64 + k];
            }
            #pragma unroll
            for (int j = 0; j < 4; ++j) {
                int row = wn*64 + j*16 + (lane & 15);
                int k   = ks*32 + (lane >> 4)*8;
                bf[j] = *(const short8*)&lB[row*64 + k];
            }
            #pragma unroll
            for (int i = 0; i < 4; ++i)
                #pragma unroll
                for (int j = 0; j < 4; ++j)
                    acc[i][j] = __builtin_amdgcn_mfma_f32_16x16x32_bf16(af[i], bf[j], acc[i][j], 0, 0, 0);
        }
    }

    #pragma unroll
    for (int i = 0; i < 4; ++i) {
        int rbase = rowA0 + wm*64 + i*16 + (lane >> 4)*4;
        #pragma unroll
        for (int j = 0; j < 4; ++j) {
            int c = rowB0 + wn*64 + j*16 + (lane & 15);
            float bqv = bq[c];
            #pragma unroll
            for (int reg = 0; reg < 4; ++reg)
                C[(size_t)(rbase + reg)*VOC + c] = acc[i][j][reg] + bqv;
        }
    }
}

// ---------------------------------------------------------------------------
extern "C" void kernel_launch(void* const* d_in, const int* in_sizes, int n_in,
                              void* d_out, int out_size, void* d_ws, size_t ws_size,
                              hipStream_t stream) {
    const int*   X   = (const int*)d_in[0];
    const float* H0  = (const float*)d_in[1];
    const float* Wxh = (const float*)d_in[2];
    const float* Whh = (const float*)d_in[3];
    const float* bh  = (const float*)d_in[4];
    const float* Whq = (const float*)d_in[5];
    const float* bq  = (const float*)d_in[6];
    float* out = (float*)d_out;

    // workspace layout
    char* ws = (char*)d_ws;
    unsigned* bar = (unsigned*)ws;                                            // 4 KB
    unsigned* pf  = (unsigned*)(ws + 4096);                                   // 513*4*64*4 B flags
    unsigned short* WhhT = (unsigned short*)(ws + 4096 + (1u<<20));           // 2 MB
    unsigned short* BtHq = (unsigned short*)(ws + 4096 + (1u<<20) + (size_t)2*1024*1024);
    unsigned short* Hst  = (unsigned short*)(ws + 4096 + (1u<<20) + (size_t)10*1024*1024);

    // barrier + flags must start at 0 on EVERY call (graph replays included)
    hipMemsetAsync(bar, 0, 4096, stream);
    hipMemsetAsync(pf, 0, (size_t)PFN * sizeof(unsigned), stream);

    k_transpose_f32_bf16<<<dim3(HID/64, HID/64), 256, 0, stream>>>(Whh, WhhT, HID, HID);
    k_transpose_f32_bf16<<<dim3(VOC/64, HID/64), 256, 0, stream>>>(Whq, BtHq, HID, VOC);

    float* Hfin = out + (size_t)LROWS * VOC;
    // Cooperative launch: guarantees all 64 wgs co-resident (dataflow spin
    // and init barrier both need it). Proven at this resource profile.
    {
        const unsigned short* a0 = WhhT;
        const float* a1 = bh;
        const float* a2 = Wxh;
        const int*   a3 = X;
        const float* a4 = H0;
        unsigned short* a5 = Hst;
        float* a6 = Hfin;
        unsigned* a7 = bar;
        unsigned* a8 = pf;
        void* args[] = { &a0, &a1, &a2, &a3, &a4, &a5, &a6, &a7, &a8 };
        hipLaunchCooperativeKernel((void*)k_rnn_persist, dim3(NWG), dim3(256),
                                   args, 0, stream);
    }

    k_gemm_logits<<<dim3(LROWS/128, VOC/128), 256, 0, stream>>>(Hst + HN, BtHq, bq, out);
}

// Round 10
// 2655.253 us; speedup vs baseline: 1.6808x; 1.6808x over previous
//
#include <hip/hip_runtime.h>
#include <hip/hip_bf16.h>
#include <stdint.h>

#define BATCH 64
#define SEQ   512
#define HID   1024
#define VOC   4096
#define LROWS (SEQ*BATCH)   // 32768 output rows
#define NGRP  8             // independent batch-row groups
#define RPG   8             // batch rows per group
#define NWK   32            // worker wgs per group (32 cols each)
#define CPW   32            // hidden cols per worker

// ctrl layout (u32 word indices)
#define CNT_BASE   0        // 8 claim counters, stride 32 words
#define BAR_CNT    256      // init barrier arrival counter
#define BAR_REL    288      // init barrier release flag
#define FFLG       512                  // fast flags [SEQ][NGRP][64]
#define SFLG       (512 + SEQ*NGRP*64)  // slow flags [SEQ][NGRP][64]
#define CTRL_WORDS (512 + 2*SEQ*NGRP*64)

typedef __attribute__((ext_vector_type(4))) float f32x4;
typedef __attribute__((ext_vector_type(8))) short short8;

__device__ __forceinline__ unsigned short f2bf(float f) {
    unsigned int u = __builtin_bit_cast(unsigned int, f);
    u += 0x7fffu + ((u >> 16) & 1u);   // round-to-nearest-even
    return (unsigned short)(u >> 16);
}

__device__ __forceinline__ float tanh_fast(float x) {
    float e = __expf(2.f * x);
    return (e - 1.f) * __frcp_rn(e + 1.f);
}

// sc0sc1 write-through store: visible device-wide once vmcnt retires (proven r4-r8)
__device__ __forceinline__ void st_bf16_llc(unsigned short* p, unsigned short v) {
    unsigned vv = v;
    asm volatile("global_store_short %0, %1, off sc0 sc1" :: "v"(p), "v"(vv) : "memory");
}
// fast flag: plain store (lands in producer's L2; same-XCD readers see it)
__device__ __forceinline__ void st_flag_fast(unsigned* p, unsigned v) {
    asm volatile("global_store_dword %0, %1, off" :: "v"(p), "v"(v) : "memory");
}
// fast poll: sc0 load = bypass L1, read (shared) L2
__device__ __forceinline__ unsigned ld_flag_fast(const unsigned* p) {
    unsigned v;
    asm volatile("global_load_dword %0, %1, off sc0\ns_waitcnt vmcnt(0)"
                 : "=v"(v) : "v"(p) : "memory");
    return v;
}

// async global->LDS, 16B per lane (gemm only)
#define GLL16(g, l) __builtin_amdgcn_global_load_lds( \
    (const __attribute__((address_space(1))) void*)(g), \
    (__attribute__((address_space(3))) void*)(l), 16, 0, 0)

// ---------------------------------------------------------------------------
// Generic: in[R][C] f32  ->  out[C][R] bf16   (transpose + convert)
// ---------------------------------------------------------------------------
__global__ __launch_bounds__(256) void k_transpose_f32_bf16(
    const float* __restrict__ in, unsigned short* __restrict__ out, int R, int C)
{
    __shared__ float tile[64][65];
    const int tid = threadIdx.x;
    const int c0 = blockIdx.x * 64;
    const int r0 = blockIdx.y * 64;
    #pragma unroll
    for (int i = 0; i < 16; ++i) {
        int idx = tid + i*256;
        int r = idx >> 6, c = idx & 63;
        tile[r][c] = in[(size_t)(r0 + r)*C + c0 + c];
    }
    __syncthreads();
    #pragma unroll
    for (int i = 0; i < 16; ++i) {
        int idx = tid + i*256;
        int r = idx >> 6, c = idx & 63;
        out[(size_t)(c0 + r)*R + r0 + c] = f2bf(tile[c][r]);
    }
}

// ---------------------------------------------------------------------------
// Persistent recurrence: 256 wgs x 128 thr (2 waves), cooperative.
// Group g (8 groups) owns batch rows [8g,8g+8); worker slot s owns cols
// [32s,32s+32); wave w covers cols [32s+16w, +16). A-rows 8..15 of the
// 16x16 MFMA duplicate rows 0..7 (pad; dup results discarded).
// Sync: per-(worker,wave) DUAL flags -- plain fast flag (L2-local when
// producer/consumer share an XCD) + relaxed-atomic slow flag (LLC, proven).
// Correctness NEVER depends on placement or XCC_ID; fast path is purely
// opportunistic. Data always goes sc0sc1 -> LLC before flags.
// ---------------------------------------------------------------------------
__global__ __launch_bounds__(128, 1) void k_rnn_persist(
    const unsigned short* __restrict__ WhhT, // [1024 c][1024 k] bf16
    const float* __restrict__ bh,
    const float* __restrict__ Wxh,           // [4096][1024] f32
    const int*   __restrict__ X,             // [64][512]
    const float* __restrict__ H0,            // [64][1024] f32
    unsigned short* __restrict__ H0s,        // [64][1024] bf16 staging
    unsigned short* __restrict__ Agem,       // [512*64][1024] bf16 (gemm A)
    float* __restrict__ Hfin,
    unsigned* __restrict__ ctrl)             // zeroed per call
{
    __shared__ unsigned short Wl[CPW*HID];   // 64 KB, [c][k] XOR-swizzled
    __shared__ int s_g, s_slot;
    const int tid  = threadIdx.x;
    const int lane = tid & 63;
    const int wave = tid >> 6;

    // one-time L2 invalidate: clears any stale lines from prior replays
    __builtin_amdgcn_fence(__ATOMIC_ACQUIRE, "agent");

    unsigned xcd;
    asm volatile("s_getreg_b32 %0, hwreg(HW_REG_XCC_ID)" : "=s"(xcd));

    // ---- claim a (group, slot): own-XCD affinity first, cyclic fallback.
    // Affinity is a HINT only; any placement is correct (dual flags).
    if (tid == 0) {
        int gg = 0, ss = 0;
        for (int i = 0; i < NGRP; ++i) {
            int cand = (int)((xcd + i) & 7);
            unsigned s = atomicAdd(ctrl + CNT_BASE + cand*32, 1u);
            if (s < NWK) { gg = cand; ss = (int)s; break; }
        }
        s_g = gg; s_slot = ss;
    }
    __syncthreads();
    const int g = s_g, slot = s_slot;

    // ---- stage W_hh^T col-slice into LDS (swizzle: byte ^= (c&7)<<4) ----
    #pragma unroll
    for (int it = 0; it < 32; ++it) {
        int sl = it*128 + tid;               // 0..4095 16B chunks
        int cc = sl >> 7;                    // 0..31
        int k0 = (sl & 127) * 8;
        short8 v = *(const short8*)&WhhT[(size_t)(slot*CPW + cc)*HID + k0];
        int byte = cc*2048 + k0*2;
        byte ^= (cc & 7) << 4;
        *(short8*)((char*)Wl + byte) = v;
    }
    // ---- stage my H0 slice (bf16) at LLC ----
    for (int i = tid; i < RPG*CPW; i += 128) {
        int r = i >> 5, cc = i & 31;
        int b = g*RPG + r, gc = slot*CPW + cc;
        st_bf16_llc(&H0s[b*HID + gc], f2bf(H0[b*HID + gc]));
    }
    // ---- one-time flat init barrier over all 256 wgs (proven r4 scheme) ----
    asm volatile("s_waitcnt vmcnt(0)" ::: "memory");
    __syncthreads();
    if (tid == 0) {
        unsigned old = __hip_atomic_fetch_add(ctrl + BAR_CNT, 1u,
                                              __ATOMIC_RELAXED, __HIP_MEMORY_SCOPE_AGENT);
        if (old == NGRP*NWK - 1u) {
            __hip_atomic_store(ctrl + BAR_REL, 1u,
                               __ATOMIC_RELAXED, __HIP_MEMORY_SCOPE_AGENT);
        } else {
            unsigned r; long it = 0;
            do {
                __builtin_amdgcn_s_sleep(1);
                r = __hip_atomic_load(ctrl + BAR_REL,
                                      __ATOMIC_RELAXED, __HIP_MEMORY_SCOPE_AGENT);
            } while (r == 0u && ++it < (1L << 24));   // fail visibly, never hang
        }
    }
    __syncthreads();

    const int col   = slot*CPW + wave*16 + (lane & 15);
    const float bhc = bh[col];
    const int c     = wave*16 + (lane & 15);     // Wl row
    const int rq    = (lane >> 4) & 1;           // row-quad (dup for lanes>=32)

    float xv[4];
    #pragma unroll
    for (int q = 0; q < 4; ++q)
        xv[q] = Wxh[(size_t)X[(g*RPG + rq*4 + q)*SEQ + 0]*HID + col];

    for (int t = 0; t < SEQ; ++t) {
        // ---- wait for my group's 64 producer-wave flags of step t ----
        if (t > 0) {
            const size_t fi = ((size_t)t*NGRP + g)*64 + lane;
            const unsigned* ff = ctrl + FFLG + fi;
            const unsigned* sf = ctrl + SFLG + fi;
            unsigned v = 0; int it = 0;
            while (true) {
                if (v == 0u) v = ld_flag_fast(ff);
                if (__ballot(v == 0u) == 0ull) break;
                if (v == 0u && (it & 3) == 3)
                    v = __hip_atomic_load(sf, __ATOMIC_RELAXED,
                                          __HIP_MEMORY_SCOPE_AGENT);
                if (__ballot(v == 0u) == 0ull) break;
                if (it > 64) __builtin_amdgcn_s_sleep(1);
                if (++it > (1 << 20)) break;   // visible failure, no 600s hang
            }
        }

        const unsigned short* src = (t == 0) ? H0s
                                             : Agem + (size_t)(t - 1)*BATCH*HID;
        const unsigned short* arow =
            src + (size_t)(g*RPG + (lane & 7))*HID + (lane >> 4)*8;
        short8 af[32];
        #pragma unroll
        for (int ks = 0; ks < 32; ++ks)
            af[ks] = *(const short8*)(arow + ks*32);

        float xvn[4] = {0.f, 0.f, 0.f, 0.f};
        if (t + 1 < SEQ) {
            #pragma unroll
            for (int q = 0; q < 4; ++q)
                xvn[q] = Wxh[(size_t)X[(g*RPG + rq*4 + q)*SEQ + (t + 1)]*HID + col];
        }

        f32x4 acc0 = (f32x4){0.f,0.f,0.f,0.f};
        f32x4 acc1 = (f32x4){0.f,0.f,0.f,0.f};
        #pragma unroll
        for (int ks = 0; ks < 32; ks += 2) {
            int byte0 = c*2048 + ks*64 + (lane >> 4)*16;
            int byte1 = byte0 + 64;
            byte0 ^= (lane & 7) << 4;
            byte1 ^= (lane & 7) << 4;
            short8 b0 = *(const short8*)((const char*)Wl + byte0);
            short8 b1 = *(const short8*)((const char*)Wl + byte1);
            acc0 = __builtin_amdgcn_mfma_f32_16x16x32_bf16(af[ks],   b0, acc0, 0,0,0);
            acc1 = __builtin_amdgcn_mfma_f32_16x16x32_bf16(af[ks+1], b1, acc1, 0,0,0);
        }
        f32x4 acc = acc0 + acc1;

        unsigned short* orow = Agem + (size_t)t*BATCH*HID;
        if ((lane >> 4) < 2) {    // rows 0..7 real, rest are pad duplicates
            #pragma unroll
            for (int q = 0; q < 4; ++q) {
                int b = g*RPG + (lane >> 4)*4 + q;
                float h = tanh_fast(acc[q] + xv[q] + bhc);
                st_bf16_llc(&orow[(size_t)b*HID + col], f2bf(h));
                if (t == SEQ - 1) Hfin[b*HID + col] = h;
            }
        }
        #pragma unroll
        for (int q = 0; q < 4; ++q) xv[q] = xvn[q];

        // ---- publish: drain data to LLC, then set BOTH flags ----
        if (t + 1 < SEQ) {
            asm volatile("s_waitcnt vmcnt(0)" ::: "memory");
            if (lane == 0) {
                size_t fi = ((size_t)(t + 1)*NGRP + g)*64 + slot*2 + wave;
                st_flag_fast(ctrl + FFLG + fi, 1u);
                __hip_atomic_store(ctrl + SFLG + fi, 1u,
                                   __ATOMIC_RELAXED, __HIP_MEMORY_SCOPE_AGENT);
            }
        }
        // t == SEQ-1: stores drain at kernel end (stream order before gemm)
    }
}

// ---------------------------------------------------------------------------
// Logits GEMM: C[L][4096] = A[L][1024](bf16) * Bt[4096][1024]^T(bf16) + b_q
// 128x128 tile, BK=64, 4 waves (2x2); XCD-aware block swizzle
// ---------------------------------------------------------------------------
__global__ __launch_bounds__(256) void k_gemm_logits(
    const unsigned short* __restrict__ A,
    const unsigned short* __restrict__ Bt,
    const float* __restrict__ bq,
    float* __restrict__ C)
{
    __shared__ unsigned short lA[128*64];
    __shared__ unsigned short lB[128*64];
    const int tid  = threadIdx.x;
    const int lane = tid & 63;
    const int wave = tid >> 6;
    const int wm = wave >> 1, wn = wave & 1;

    const int NBM = LROWS/128, NBN = VOC/128;          // 256 x 32 = 8192
    int lid = blockIdx.y * NBM + blockIdx.x;
    int swz = (lid & 7) * (NBM*NBN/8) + (lid >> 3);
    const int bm = swz % NBM;
    const int bn = swz / NBM;
    const int rowA0 = bm * 128;
    const int rowB0 = bn * 128;

    f32x4 acc[4][4];
    #pragma unroll
    for (int i = 0; i < 4; ++i)
        #pragma unroll
        for (int j = 0; j < 4; ++j)
            acc[i][j] = (f32x4){0.f, 0.f, 0.f, 0.f};

    for (int kt = 0; kt < HID; kt += 64) {
        __syncthreads();
        #pragma unroll
        for (int i = 0; i < 4; ++i) {
            int slot = i*256 + tid;
            int row  = slot >> 3;
            int colb = (slot & 7) * 8;
            const unsigned short* ga = A  + (size_t)(rowA0 + row)*HID + kt + colb;
            const unsigned short* gb = Bt + (size_t)(rowB0 + row)*HID + kt + colb;
            unsigned short* la = lA + (i*256 + (tid >> 6)*64)*8;
            unsigned short* lb = lB + (i*256 + (tid >> 6)*64)*8;
            GLL16(ga, la);
            GLL16(gb, lb);
        }
        __syncthreads();
        #pragma unroll
        for (int ks = 0; ks < 2; ++ks) {
            short8 af[4], bf[4];
            #pragma unroll
            for (int i = 0; i < 4; ++i) {
                int row = wm*64 + i*16 + (lane & 15);
                int k   = ks*32 + (lane >> 4)*8;
                af[i] = *(const short8*)&lA[row*64 + k];
            }
            #pragma unroll
            for (int j = 0; j < 4; ++j) {
                int row = wn*64 + j*16 + (lane & 15);
                int k   = ks*32 + (lane >> 4)*8;
                bf[j] = *(const short8*)&lB[row*64 + k];
            }
            #pragma unroll
            for (int i = 0; i < 4; ++i)
                #pragma unroll
                for (int j = 0; j < 4; ++j)
                    acc[i][j] = __builtin_amdgcn_mfma_f32_16x16x32_bf16(af[i], bf[j], acc[i][j], 0, 0, 0);
        }
    }

    #pragma unroll
    for (int i = 0; i < 4; ++i) {
        int rbase = rowA0 + wm*64 + i*16 + (lane >> 4)*4;
        #pragma unroll
        for (int j = 0; j < 4; ++j) {
            int cc = rowB0 + wn*64 + j*16 + (lane & 15);
            float bqv = bq[cc];
            #pragma unroll
            for (int reg = 0; reg < 4; ++reg)
                C[(size_t)(rbase + reg)*VOC + cc] = acc[i][j][reg] + bqv;
        }
    }
}

// ---------------------------------------------------------------------------
extern "C" void kernel_launch(void* const* d_in, const int* in_sizes, int n_in,
                              void* d_out, int out_size, void* d_ws, size_t ws_size,
                              hipStream_t stream) {
    const int*   X   = (const int*)d_in[0];
    const float* H0  = (const float*)d_in[1];
    const float* Wxh = (const float*)d_in[2];
    const float* Whh = (const float*)d_in[3];
    const float* bh  = (const float*)d_in[4];
    const float* Whq = (const float*)d_in[5];
    const float* bq  = (const float*)d_in[6];
    float* out = (float*)d_out;

    // workspace layout
    char* ws = (char*)d_ws;
    unsigned* ctrl = (unsigned*)ws;                                       // ~2.1 MB
    unsigned short* WhhT = (unsigned short*)(ws + (size_t)4*1024*1024);   // 2 MB
    unsigned short* BtHq = (unsigned short*)(ws + (size_t)8*1024*1024);   // 8 MB
    unsigned short* H0s  = (unsigned short*)(ws + (size_t)16*1024*1024);  // 128 KB
    unsigned short* Agem = (unsigned short*)(ws + (size_t)20*1024*1024);  // 64 MB

    hipMemsetAsync(ctrl, 0, (size_t)CTRL_WORDS * sizeof(unsigned), stream);

    k_transpose_f32_bf16<<<dim3(HID/64, HID/64), 256, 0, stream>>>(Whh, WhhT, HID, HID);
    k_transpose_f32_bf16<<<dim3(VOC/64, HID/64), 256, 0, stream>>>(Whq, BtHq, HID, VOC);

    float* Hfin = out + (size_t)LROWS * VOC;
    {
        const unsigned short* a0 = WhhT;
        const float* a1 = bh;
        const float* a2 = Wxh;
        const int*   a3 = X;
        const float* a4 = H0;
        unsigned short* a5 = H0s;
        unsigned short* a6 = Agem;
        float* a7 = Hfin;
        unsigned* a8 = ctrl;
        void* args[] = { &a0, &a1, &a2, &a3, &a4, &a5, &a6, &a7, &a8 };
        hipLaunchCooperativeKernel((void*)k_rnn_persist, dim3(NGRP*NWK), dim3(128),
                                   args, 0, stream);
    }

    k_gemm_logits<<<dim3(LROWS/128, VOC/128), 256, 0, stream>>>(Agem, BtHq, bq, out);
}